// Round 1
// baseline (8737.034 us; speedup 1.0000x reference)
//
#include <hip/hip_runtime.h>
#include <hip/hip_bf16.h>
#include <math.h>

typedef __hip_bfloat16 bf16;

#define TPB 512
#define WN 169
#define LPAD 8
#define RS (WN + LPAD)   // 177
#define DIN 64
#define CH 128
#define TPQ 24
#define BQ 128
#define LSQ 168

__device__ __forceinline__ float b2f(bf16 v) { return __bfloat162float(v); }
__device__ __forceinline__ bf16 f2b(float v) { return __float2bfloat16(v); }

// Conv: out[co,w] = relu(bias[co] + sum_{ci,k} w[co,ci,k]*in[ci, w-(2-k)*DIL])
// RESMODE 0: plain. RESMODE 1: out = relu(relu(conv+b) + resbuf[co,w]).
template<int CIN, int DIL, int RESMODE>
__device__ __forceinline__ void conv_phase(
    const bf16* __restrict__ in, bf16* __restrict__ out,
    const float* __restrict__ w, const float* __restrict__ bias,
    const bf16* __restrict__ resbuf, int tid)
{
    const int lane = tid & 63;
    const int co0 = __builtin_amdgcn_readfirstlane((tid >> 6) << 4);
    float acc0[16], acc1[16], acc2[16];
#pragma unroll
    for (int i = 0; i < 16; ++i) { acc0[i] = 0.f; acc1[i] = 0.f; acc2[i] = 0.f; }
    const int p0 = lane, p1 = lane + 64, p2 = lane + 128;
    const int q2 = (p2 < WN) ? p2 : (WN - 1);
    for (int ci = 0; ci < CIN; ++ci) {
        const bf16* row = in + ci * RS + LPAD;
        const float x00 = b2f(row[p0]);
        const float x01 = b2f(row[p0 - DIL]);
        const float x02 = b2f(row[p0 - 2 * DIL]);
        const float x10 = b2f(row[p1]);
        const float x11 = b2f(row[p1 - DIL]);
        const float x12 = b2f(row[p1 - 2 * DIL]);
        const float x20 = b2f(row[q2]);
        const float x21 = b2f(row[q2 - DIL]);
        const float x22 = b2f(row[q2 - 2 * DIL]);
        const float* wp = w + ((size_t)(co0 * CIN + ci)) * 3;
#pragma unroll
        for (int cg = 0; cg < 16; ++cg) {
            const float wk0 = wp[cg * CIN * 3 + 0];
            const float wk1 = wp[cg * CIN * 3 + 1];
            const float wk2 = wp[cg * CIN * 3 + 2];
            acc0[cg] = fmaf(wk2, x00, fmaf(wk1, x01, fmaf(wk0, x02, acc0[cg])));
            acc1[cg] = fmaf(wk2, x10, fmaf(wk1, x11, fmaf(wk0, x12, acc1[cg])));
            acc2[cg] = fmaf(wk2, x20, fmaf(wk1, x21, fmaf(wk0, x22, acc2[cg])));
        }
    }
#pragma unroll
    for (int cg = 0; cg < 16; ++cg) {
        const int co = co0 + cg;
        const float bv = bias[co];
        float v0 = fmaxf(acc0[cg] + bv, 0.f);
        float v1 = fmaxf(acc1[cg] + bv, 0.f);
        float v2 = fmaxf(acc2[cg] + bv, 0.f);
        if (RESMODE == 1) {
            v0 = fmaxf(v0 + b2f(resbuf[co * RS + LPAD + p0]), 0.f);
            v1 = fmaxf(v1 + b2f(resbuf[co * RS + LPAD + p1]), 0.f);
            if (p2 < WN)
                v2 = fmaxf(v2 + b2f(resbuf[co * RS + LPAD + p2]), 0.f);
        }
        out[co * RS + LPAD + p0] = f2b(v0);
        out[co * RS + LPAD + p1] = f2b(v1);
        if (p2 < WN) out[co * RS + LPAD + p2] = f2b(v2);
    }
}

// Downsample conv (K=1, Cin=64), NO relu: out[co,w] = bd[co] + sum_ci wd[co,ci]*in[ci,w]
__device__ __forceinline__ void convd_phase(
    const bf16* __restrict__ in, bf16* __restrict__ out,
    const float* __restrict__ wd, const float* __restrict__ bd, int tid)
{
    const int lane = tid & 63;
    const int co0 = __builtin_amdgcn_readfirstlane((tid >> 6) << 4);
    float acc0[16], acc1[16], acc2[16];
#pragma unroll
    for (int i = 0; i < 16; ++i) { acc0[i] = 0.f; acc1[i] = 0.f; acc2[i] = 0.f; }
    const int p0 = lane, p1 = lane + 64, p2 = lane + 128;
    const int q2 = (p2 < WN) ? p2 : (WN - 1);
    for (int ci = 0; ci < DIN; ++ci) {
        const bf16* row = in + ci * RS + LPAD;
        const float x0 = b2f(row[p0]);
        const float x1 = b2f(row[p1]);
        const float x2 = b2f(row[q2]);
        const float* wp = wd + co0 * DIN + ci;
#pragma unroll
        for (int cg = 0; cg < 16; ++cg) {
            const float wv = wp[cg * DIN];
            acc0[cg] = fmaf(wv, x0, acc0[cg]);
            acc1[cg] = fmaf(wv, x1, acc1[cg]);
            acc2[cg] = fmaf(wv, x2, acc2[cg]);
        }
    }
#pragma unroll
    for (int cg = 0; cg < 16; ++cg) {
        const int co = co0 + cg;
        const float bv = bd[co];
        out[co * RS + LPAD + p0] = f2b(acc0[cg] + bv);
        out[co * RS + LPAD + p1] = f2b(acc1[cg] + bv);
        if (p2 < WN) out[co * RS + LPAD + p2] = f2b(acc2[cg] + bv);
    }
}

extern "C" __global__ void __launch_bounds__(TPB, 1)
tcn_entmax_kernel(
    const float* __restrict__ src, const float* __restrict__ trg,
    const float* __restrict__ w01, const float* __restrict__ b01,
    const float* __restrict__ w02, const float* __restrict__ b02,
    const float* __restrict__ wd0, const float* __restrict__ bd0,
    const float* __restrict__ w11, const float* __restrict__ b11,
    const float* __restrict__ w12, const float* __restrict__ b12,
    const float* __restrict__ w21, const float* __restrict__ b21,
    const float* __restrict__ w22, const float* __restrict__ b22,
    const float* __restrict__ h1w, const float* __restrict__ h1b,
    const float* __restrict__ h2w, const float* __restrict__ h2b,
    float* __restrict__ out)
{
    __shared__ __align__(16) bf16 sX[DIN * RS];   // 22656 B, reused as fp32 scratch in attention
    __shared__ __align__(16) bf16 sA[CH * RS];    // 45312 B
    __shared__ __align__(16) bf16 sB[CH * RS];
    __shared__ __align__(16) bf16 sC[CH * RS];

    const int tid = threadIdx.x;
    const int n = blockIdx.x;
    const int tp = n >> 7;      // n / 128
    const int b  = n & 127;     // n % 128

    // ---- Phase 0: stage window into sX (bf16), zero left-pads of all buffers ----
    const float* srcb = src + (size_t)b * LSQ * DIN;
    const float* trgb = trg + (size_t)b * TPQ * DIN;
    for (int e = tid; e < WN * DIN; e += TPB) {
        const int wpos = e >> 6, d = e & 63;
        const int t = tp + wpos;
        const float v = (t < LSQ) ? srcb[t * DIN + d] : trgb[(t - LSQ) * DIN + d];
        sX[d * RS + LPAD + wpos] = f2b(v);
    }
    for (int e = tid; e < DIN * LPAD; e += TPB) {
        const int ci = e >> 3, j = e & 7;
        sX[ci * RS + j] = f2b(0.f);
    }
    for (int e = tid; e < CH * LPAD; e += TPB) {
        const int ci = e >> 3, j = e & 7;
        sA[ci * RS + j] = f2b(0.f);
        sB[ci * RS + j] = f2b(0.f);
        sC[ci * RS + j] = f2b(0.f);
    }
    __syncthreads();

    // ---- TCN block 0 (dil 1, downsample residual) ----
    conv_phase<DIN, 1, 0>(sX, sA, w01, b01, nullptr, tid);  __syncthreads();
    convd_phase(sX, sB, wd0, bd0, tid);                     __syncthreads();
    conv_phase<CH, 1, 1>(sA, sB, w02, b02, sB, tid);        __syncthreads();
    // ---- TCN block 1 (dil 2, identity residual) ----
    conv_phase<CH, 2, 0>(sB, sA, w11, b11, nullptr, tid);   __syncthreads();
    conv_phase<CH, 2, 1>(sA, sC, w12, b12, sB, tid);        __syncthreads();
    // ---- TCN block 2 (dil 4, identity residual) ----
    conv_phase<CH, 4, 0>(sC, sA, w21, b21, nullptr, tid);   __syncthreads();
    conv_phase<CH, 4, 1>(sA, sB, w22, b22, sC, tid);        __syncthreads();

    // ---- Attention + entmax15 + heads (sB holds tcn2 output [128][177]) ----
    float* fscr = reinterpret_cast<float*>(sX);
    float* xe   = fscr;          // 168: scores, then (s-max)/2
    float* xs   = fscr + 168;    // 168: sorted desc
    float* stau = fscr + 336;    // 168
    float* ssc  = fscr + 504;    // 168: entmax output
    float* qv   = fscr + 672;    // 128
    float* cv   = fscr + 800;    // 128
    float* csA_ = fscr + 928;    // 168
    float* csB_ = fscr + 1096;   // 168
    float* c2A_ = fscr + 1264;   // 168
    float* c2B_ = fscr + 1432;   // 168
    float* red1 = fscr + 1600;   // 512
    float* red2 = fscr + 2112;   // 512

    if (tid < CH) qv[tid] = b2f(sB[tid * RS + LPAD + 168]);
    __syncthreads();

    if (tid < LSQ) {
        float s = 0.f;
        for (int c = 0; c < CH; ++c) s = fmaf(qv[c], b2f(sB[c * RS + LPAD + tid]), s);
        xe[tid] = s;
    }
    __syncthreads();

    // max over 168 scores
    red1[tid] = (tid < LSQ) ? xe[tid] : -1e30f;
    __syncthreads();
    for (int s = TPB / 2; s > 0; s >>= 1) {
        if (tid < s) red1[tid] = fmaxf(red1[tid], red1[tid + s]);
        __syncthreads();
    }
    const float mx = red1[0];
    __syncthreads();

    if (tid < LSQ) xe[tid] = (xe[tid] - mx) * 0.5f;
    __syncthreads();

    // sort descending via pairwise rank (stable on ties by index)
    if (tid < LSQ) {
        const float v = xe[tid];
        int r = 0;
        for (int m2 = 0; m2 < LSQ; ++m2) {
            const float u = xe[m2];
            r += (u > v) || ((u == v) && (m2 < tid));
        }
        xs[r] = v;
    }
    __syncthreads();

    // inclusive cumsum of xs and xs^2 (Hillis-Steele, ping-pong)
    if (tid < LSQ) { csA_[tid] = xs[tid]; c2A_[tid] = xs[tid] * xs[tid]; }
    __syncthreads();
    {
        float *pa = csA_, *pb = csB_, *qa = c2A_, *qb = c2B_;
        for (int off = 1; off < LSQ; off <<= 1) {
            if (tid < LSQ) {
                float a = pa[tid], a2 = qa[tid];
                if (tid >= off) { a += pa[tid - off]; a2 += qa[tid - off]; }
                pb[tid] = a; qb[tid] = a2;
            }
            __syncthreads();
            float* t1 = pa; pa = pb; pb = t1;
            float* t2 = qa; qa = qb; qb = t2;
        }
        if (tid < LSQ) {
            const float rho  = (float)(tid + 1);
            const float mean = pa[tid] / rho;
            const float msq  = qa[tid] / rho;
            const float ss   = rho * (msq - mean * mean);
            const float delta = (1.f - ss) / rho;
            const float dnz  = delta > 0.f ? delta : 0.f;
            const float t    = mean - sqrtf(dnz);
            stau[tid] = t;
            red1[tid] = (t <= xs[tid]) ? 1.f : 0.f;
        } else {
            red1[tid] = 0.f;
        }
    }
    __syncthreads();
    for (int s = TPB / 2; s > 0; s >>= 1) {
        if (tid < s) red1[tid] += red1[tid + s];
        __syncthreads();
    }
    const int support = (int)(red1[0] + 0.5f);
    const float tau_star = stau[support - 1];
    __syncthreads();

    if (tid < LSQ) {
        float v = xe[tid] - tau_star;
        v = fmaxf(v, 0.f);
        ssc[tid] = v * v;
    }
    __syncthreads();

    // context vector c = sum_l score_l * kv[l][:]
    if (tid < CH) {
        float a = 0.f;
        for (int l = 0; l < LSQ; ++l) a = fmaf(ssc[l], b2f(sB[tid * RS + LPAD + l]), a);
        cv[tid] = a;
    }
    __syncthreads();

    // heads: cc = [c, q] (256), y1 = h1w.cc + h1b ; y2 = softplus(h2w.cc + h2b)
    float p1 = 0.f, p2v = 0.f;
    if (tid < CH)          { p1 = h1w[tid] * cv[tid];       p2v = h2w[tid] * cv[tid]; }
    else if (tid < 2 * CH) { p1 = h1w[tid] * qv[tid - CH];  p2v = h2w[tid] * qv[tid - CH]; }
    red1[tid] = p1; red2[tid] = p2v;
    __syncthreads();
    for (int s = TPB / 2; s > 0; s >>= 1) {
        if (tid < s) { red1[tid] += red1[tid + s]; red2[tid] += red2[tid + s]; }
        __syncthreads();
    }
    if (tid == 0) {
        const float y1 = red1[0] + h1b[0];
        const float z  = red2[0] + h2b[0];
        const float sp = (z > 0.f) ? (z + log1pf(expf(-z))) : log1pf(expf(z));
        out[b * TPQ + tp] = y1;
        out[BQ * TPQ + b * TPQ + tp] = sp;
    }
}

extern "C" void kernel_launch(void* const* d_in, const int* in_sizes, int n_in,
                              void* d_out, int out_size, void* d_ws, size_t ws_size,
                              hipStream_t stream) {
    const float* src = (const float*)d_in[0];
    const float* trg = (const float*)d_in[1];
    const float* w01 = (const float*)d_in[2];
    const float* b01 = (const float*)d_in[3];
    const float* w02 = (const float*)d_in[4];
    const float* b02 = (const float*)d_in[5];
    const float* wd0 = (const float*)d_in[6];
    const float* bd0 = (const float*)d_in[7];
    const float* w11 = (const float*)d_in[8];
    const float* b11 = (const float*)d_in[9];
    const float* w12 = (const float*)d_in[10];
    const float* b12 = (const float*)d_in[11];
    const float* w21 = (const float*)d_in[12];
    const float* b21 = (const float*)d_in[13];
    const float* w22 = (const float*)d_in[14];
    const float* b22 = (const float*)d_in[15];
    const float* h1w = (const float*)d_in[16];
    const float* h1b = (const float*)d_in[17];
    const float* h2w = (const float*)d_in[18];
    const float* h2b = (const float*)d_in[19];

    dim3 grid(TPQ * BQ);   // 3072 sequences
    dim3 block(TPB);
    tcn_entmax_kernel<<<grid, block, 0, stream>>>(
        src, trg, w01, b01, w02, b02, wd0, bd0,
        w11, b11, w12, b12, w21, b21, w22, b22,
        h1w, h1b, h2w, h2b, (float*)d_out);
}

// Round 2
// 757.391 us; speedup vs baseline: 11.5357x; 11.5357x over previous
//
#include <hip/hip_runtime.h>
#include <hip/hip_bf16.h>
#include <math.h>

typedef __hip_bfloat16 bf16;
typedef __attribute__((ext_vector_type(8))) short short8;
typedef __attribute__((ext_vector_type(4))) float f32x4;
typedef __attribute__((ext_vector_type(4))) float f4;

#define TPB 512
#define TPQ 24
#define BQ 128
#define LSQ 168
#define DIN 64
#define CH 128

// ws element offsets (bf16 elements), fragment-packed weights
#define E0 0        /* w01: 128x64x3  -> 24576 */
#define ED 24576    /* wd0: 128x64x1  -> 8192  */
#define E1 32768    /* w02 */
#define E2 81920    /* w11 */
#define E3 131072   /* w12 */
#define E4 180224   /* w21 */
#define E5 229376   /* w22 */
#define WTOT 278528 /* lo copies at ws + WTOT */

#define MFMA16(a, b, c) __builtin_amdgcn_mfma_f32_16x16x32_bf16((a), (b), (c), 0, 0, 0)

__device__ __forceinline__ short f2bs(float v) {
    bf16 h = __float2bfloat16(v); short s; __builtin_memcpy(&s, &h, 2); return s;
}
__device__ __forceinline__ float bs2f(short s) {
    bf16 h; __builtin_memcpy(&h, &s, 2); return __bfloat162float(h);
}

// byte offset of element (row8, co) in a 128-wide swizzled Xt buffer (256B rows)
__device__ __forceinline__ int xb128(int r8, int co) {
    return r8 * 256 + ((((co >> 3) ^ (r8 & 7))) << 4) + ((co & 7) << 1);
}

// ---------------- weight fragment packing (runs once per launch) ----------------
extern "C" __global__ void pack_weights(
    const float* __restrict__ w01, const float* __restrict__ wd0,
    const float* __restrict__ w02, const float* __restrict__ w11,
    const float* __restrict__ w12, const float* __restrict__ w21,
    const float* __restrict__ w22, bf16* __restrict__ ws)
{
    int e = blockIdx.x * 256 + threadIdx.x;
    if (e >= WTOT) return;
    const float* W; int CIN, KK, el;
    if (e < ED) { W = w01; CIN = 64; KK = 3; el = e; }
    else if (e < E1) { W = wd0; CIN = 64; KK = 1; el = e - ED; }
    else {
        int c = (e - E1) / 49152; el = (e - E1) % 49152; CIN = 128; KK = 3;
        W = (c == 0) ? w02 : (c == 1) ? w11 : (c == 2) ? w12 : (c == 3) ? w21 : w22;
    }
    const int KB = CIN / 32;
    const int frag = el >> 9, wi = el & 511, lane = wi >> 3, i = wi & 7;
    const int coT = frag / (KK * KB), rem = frag % (KK * KB);
    const int kk = rem / KB, kb = rem % KB;
    const int co = coT * 16 + (lane & 15);
    const int ci = kb * 32 + (lane >> 4) * 8 + i;
    const float v = W[(co * CIN + ci) * KK + kk];
    const bf16 hi = __float2bfloat16(v);
    ws[e] = hi;
    ws[WTOT + e] = __float2bfloat16(v - __bfloat162float(hi));
}

// ---------------- MFMA conv phase ----------------
// out[w][co] = act( bias + sum_{kk,ci} W[co][ci][kk] * in[ci][w - (KK-1-kk)*DIL] ), RES adds residual elementwise.
template<int CIN, int KK, int DIL, int RES, int RELU>
__device__ __forceinline__ void mfma_conv(
    const char* __restrict__ inB, char* __restrict__ outB, const char* __restrict__ resB,
    const bf16* __restrict__ wsAll, int eoff,
    const float* __restrict__ bias, int tid)
{
    constexpr int KB = CIN / 32;
    constexpr int RGB = CIN * 2;       // row bytes of input buffer
    const int lane = tid & 63;
    const int wid = tid >> 6;
    const int cg = wid & 3, wg = wid >> 2;
    const int t0 = wg ? 6 : 0, t1 = wg ? 11 : 6;
    const int colr = lane & 15;
    const int quad = lane >> 4;

    const short8* __restrict__ wp = (const short8*)(wsAll + eoff);
    const short8* __restrict__ wq = (const short8*)(wsAll + WTOT + eoff);
    short8 wfh[2][KK][KB], wfl[2][KK][KB];
#pragma unroll
    for (int ct = 0; ct < 2; ++ct)
#pragma unroll
        for (int kk = 0; kk < KK; ++kk)
#pragma unroll
            for (int kb = 0; kb < KB; ++kb) {
                const int frag = (((cg * 2 + ct) * KK + kk) * KB + kb);
                wfh[ct][kk][kb] = wp[frag * 64 + lane];
                wfl[ct][kk][kb] = wq[frag * 64 + lane];
            }
    const float bv0 = bias[cg * 32 + colr];
    const float bv1 = bias[cg * 32 + 16 + colr];

    for (int t = t0; t < t1; ++t) {
        const int w0 = t * 16;
        f32x4 acc0 = {0.f, 0.f, 0.f, 0.f}, acc1 = {0.f, 0.f, 0.f, 0.f};
        const int wr = w0 + colr + 8;
#pragma unroll
        for (int kk = 0; kk < KK; ++kk) {
            int row8 = wr - (KK - 1 - kk) * DIL;
            row8 = (row8 > 176) ? 176 : row8;
            const int rbase = row8 * RGB;
            const int sx = row8 & 7;
#pragma unroll
            for (int kb = 0; kb < KB; ++kb) {
                const int g = kb * 4 + quad;
                const short8 a = *(const short8*)(inB + rbase + ((g ^ sx) << 4));
                acc0 = MFMA16(a, wfh[0][kk][kb], acc0);
                acc1 = MFMA16(a, wfh[1][kk][kb], acc1);
                acc0 = MFMA16(a, wfl[0][kk][kb], acc0);
                acc1 = MFMA16(a, wfl[1][kk][kb], acc1);
            }
        }
#pragma unroll
        for (int j = 0; j < 4; ++j) {
            const int w = w0 + quad * 4 + j;
            if (w < 169) {
                const int r8 = w + 8;
                {
                    const int co = cg * 32 + colr;
                    float v = acc0[j] + bv0;
                    if (RELU) v = fmaxf(v, 0.f);
                    if (RES)  v = fmaxf(v + bs2f(*(const short*)(resB + xb128(r8, co))), 0.f);
                    *(short*)(outB + xb128(r8, co)) = f2bs(v);
                }
                {
                    const int co = cg * 32 + 16 + colr;
                    float v = acc1[j] + bv1;
                    if (RELU) v = fmaxf(v, 0.f);
                    if (RES)  v = fmaxf(v + bs2f(*(const short*)(resB + xb128(r8, co))), 0.f);
                    *(short*)(outB + xb128(r8, co)) = f2bs(v);
                }
            }
        }
    }
}

// ---------------- main fused kernel ----------------
extern "C" __global__ void __launch_bounds__(TPB, 1)
tcn_entmax_kernel(
    const float* __restrict__ src, const float* __restrict__ trg,
    const bf16* __restrict__ ws,
    const float* __restrict__ b01, const float* __restrict__ bd0,
    const float* __restrict__ b02, const float* __restrict__ b11,
    const float* __restrict__ b12, const float* __restrict__ b21,
    const float* __restrict__ b22,
    const float* __restrict__ h1w, const float* __restrict__ h1b,
    const float* __restrict__ h2w, const float* __restrict__ h2b,
    float* __restrict__ out)
{
    // Xt layout: [row8 = w+8][ci], bf16, 16B-granule XOR swizzle: granule ^= (row8 & 7)
    __shared__ __align__(16) char sX0[177 * 128];   // 64-ch input window
    __shared__ __align__(16) char sA[177 * 256];
    __shared__ __align__(16) char sB[177 * 256];
    __shared__ __align__(16) char sC[177 * 256];

    const int tid = threadIdx.x;
    const int n = blockIdx.x;
    const int tp = n >> 7;
    const int b = n & 127;

    // ---- stage window (transposed + swizzled), zero left-pad rows ----
    const float* srcb = src + (size_t)b * LSQ * DIN;
    const float* trgb = trg + (size_t)b * TPQ * DIN;
    for (int e = tid; e < 169 * 8; e += TPB) {
        const int w = e >> 3, g = e & 7;
        const int t = tp + w;
        const float* p = (t < LSQ) ? (srcb + t * DIN + g * 8) : (trgb + (t - LSQ) * DIN + g * 8);
        const f4 f0 = *(const f4*)p;
        const f4 f1 = *(const f4*)(p + 4);
        short8 v;
        v[0] = f2bs(f0[0]); v[1] = f2bs(f0[1]); v[2] = f2bs(f0[2]); v[3] = f2bs(f0[3]);
        v[4] = f2bs(f1[0]); v[5] = f2bs(f1[1]); v[6] = f2bs(f1[2]); v[7] = f2bs(f1[3]);
        const int r8 = w + 8;
        *(short8*)(sX0 + r8 * 128 + ((g ^ (r8 & 7)) << 4)) = v;
    }
    {
        const short8 z = {0, 0, 0, 0, 0, 0, 0, 0};
        for (int e = tid; e < 64 + 3 * 128; e += TPB) {
            if (e < 64) *(short8*)(sX0 + e * 16) = z;
            else {
                const int q = e - 64, buf = q >> 7, g = q & 127;
                char* base = (buf == 0) ? sA : (buf == 1) ? sB : sC;
                *(short8*)(base + g * 16) = z;
            }
        }
    }
    __syncthreads();

    // ---- TCN block 0 (dil 1, downsample residual) ----
    mfma_conv<64, 3, 1, 0, 1>(sX0, sA, nullptr, ws, E0, b01, tid);   // h1
    mfma_conv<64, 1, 1, 0, 0>(sX0, sB, nullptr, ws, ED, bd0, tid);   // res (no relu)
    __syncthreads();
    mfma_conv<128, 3, 1, 1, 1>(sA, sB, sB, ws, E1, b02, tid);
    __syncthreads();
    // ---- TCN block 1 (dil 2, identity residual) ----
    mfma_conv<128, 3, 2, 0, 1>(sB, sA, nullptr, ws, E2, b11, tid);
    __syncthreads();
    mfma_conv<128, 3, 2, 1, 1>(sA, sC, sB, ws, E3, b12, tid);
    __syncthreads();
    // ---- TCN block 2 (dil 4, identity residual) ----
    mfma_conv<128, 3, 4, 0, 1>(sC, sA, nullptr, ws, E4, b21, tid);
    __syncthreads();
    mfma_conv<128, 3, 4, 1, 1>(sA, sB, sC, ws, E5, b22, tid);
    __syncthreads();

    // ---- attention + entmax15 + heads; tcn out in sB (transposed, swizzled) ----
    float* fscr = reinterpret_cast<float*>(sX0);
    float* xe   = fscr;          // 168
    float* xs   = fscr + 168;    // 168 sorted desc
    float* stau = fscr + 336;    // 168
    float* ssc  = fscr + 504;    // 168
    float* qv   = fscr + 672;    // 128
    float* cv   = fscr + 800;    // 128
    float* csA_ = fscr + 928;
    float* csB_ = fscr + 1096;
    float* c2A_ = fscr + 1264;
    float* c2B_ = fscr + 1432;
    float* red1 = fscr + 1600;   // 512
    float* red2 = fscr + 2112;   // 512

    if (tid < CH) qv[tid] = bs2f(*(const short*)(sB + xb128(176, tid)));
    __syncthreads();

    if (tid < LSQ) {
        const int r8 = tid + 8, sx = r8 & 7;
        float s = 0.f;
#pragma unroll
        for (int S = 0; S < 16; ++S) {
            const short8 kvv = *(const short8*)(sB + r8 * 256 + (S << 4));
            const float* qp = qv + (S ^ sx) * 8;
#pragma unroll
            for (int j = 0; j < 8; ++j) s = fmaf(bs2f(kvv[j]), qp[j], s);
        }
        xe[tid] = s;
    }
    __syncthreads();

    red1[tid] = (tid < LSQ) ? xe[tid] : -1e30f;
    __syncthreads();
    for (int s = TPB / 2; s > 0; s >>= 1) {
        if (tid < s) red1[tid] = fmaxf(red1[tid], red1[tid + s]);
        __syncthreads();
    }
    const float mx = red1[0];
    __syncthreads();

    if (tid < LSQ) xe[tid] = (xe[tid] - mx) * 0.5f;
    __syncthreads();

    if (tid < LSQ) {
        const float v = xe[tid];
        int r = 0;
        for (int m2 = 0; m2 < LSQ; ++m2) {
            const float u = xe[m2];
            r += (u > v) || ((u == v) && (m2 < tid));
        }
        xs[r] = v;
    }
    __syncthreads();

    if (tid < LSQ) { csA_[tid] = xs[tid]; c2A_[tid] = xs[tid] * xs[tid]; }
    __syncthreads();
    {
        float *pa = csA_, *pb = csB_, *qa = c2A_, *qb = c2B_;
        for (int off = 1; off < LSQ; off <<= 1) {
            if (tid < LSQ) {
                float a = pa[tid], a2 = qa[tid];
                if (tid >= off) { a += pa[tid - off]; a2 += qa[tid - off]; }
                pb[tid] = a; qb[tid] = a2;
            }
            __syncthreads();
            float* t1 = pa; pa = pb; pb = t1;
            float* t2 = qa; qa = qb; qb = t2;
        }
        if (tid < LSQ) {
            const float rho  = (float)(tid + 1);
            const float mean = pa[tid] / rho;
            const float msq  = qa[tid] / rho;
            const float ssv  = rho * (msq - mean * mean);
            const float delta = (1.f - ssv) / rho;
            const float dnz  = delta > 0.f ? delta : 0.f;
            const float t    = mean - sqrtf(dnz);
            stau[tid] = t;
            red1[tid] = (t <= xs[tid]) ? 1.f : 0.f;
        } else {
            red1[tid] = 0.f;
        }
    }
    __syncthreads();
    for (int s = TPB / 2; s > 0; s >>= 1) {
        if (tid < s) red1[tid] += red1[tid + s];
        __syncthreads();
    }
    const int support = (int)(red1[0] + 0.5f);
    const float tau_star = stau[support - 1];
    __syncthreads();

    if (tid < LSQ) {
        float v = xe[tid] - tau_star;
        v = fmaxf(v, 0.f);
        ssc[tid] = v * v;
    }
    __syncthreads();

    if (tid < CH) {
        float a = 0.f;
        const int gco = tid >> 3, bo = (tid & 7) << 1;
        for (int l = 0; l < LSQ; ++l) {
            const int r8 = l + 8;
            a = fmaf(ssc[l], bs2f(*(const short*)(sB + r8 * 256 + (((gco ^ (r8 & 7))) << 4) + bo)), a);
        }
        cv[tid] = a;
    }
    __syncthreads();

    float p1 = 0.f, p2v = 0.f;
    if (tid < CH)          { p1 = h1w[tid] * cv[tid];       p2v = h2w[tid] * cv[tid]; }
    else if (tid < 2 * CH) { p1 = h1w[tid] * qv[tid - CH];  p2v = h2w[tid] * qv[tid - CH]; }
    red1[tid] = p1; red2[tid] = p2v;
    __syncthreads();
    for (int s = TPB / 2; s > 0; s >>= 1) {
        if (tid < s) { red1[tid] += red1[tid + s]; red2[tid] += red2[tid + s]; }
        __syncthreads();
    }
    if (tid == 0) {
        const float y1 = red1[0] + h1b[0];
        const float z  = red2[0] + h2b[0];
        const float sp = (z > 0.f) ? (z + log1pf(expf(-z))) : log1pf(expf(z));
        out[b * TPQ + tp] = y1;
        out[BQ * TPQ + b * TPQ + tp] = sp;
    }
}

extern "C" void kernel_launch(void* const* d_in, const int* in_sizes, int n_in,
                              void* d_out, int out_size, void* d_ws, size_t ws_size,
                              hipStream_t stream) {
    const float* src = (const float*)d_in[0];
    const float* trg = (const float*)d_in[1];
    const float* w01 = (const float*)d_in[2];
    const float* b01 = (const float*)d_in[3];
    const float* w02 = (const float*)d_in[4];
    const float* b02 = (const float*)d_in[5];
    const float* wd0 = (const float*)d_in[6];
    const float* bd0 = (const float*)d_in[7];
    const float* w11 = (const float*)d_in[8];
    const float* b11 = (const float*)d_in[9];
    const float* w12 = (const float*)d_in[10];
    const float* b12 = (const float*)d_in[11];
    const float* w21 = (const float*)d_in[12];
    const float* b21 = (const float*)d_in[13];
    const float* w22 = (const float*)d_in[14];
    const float* b22 = (const float*)d_in[15];
    const float* h1w = (const float*)d_in[16];
    const float* h1b = (const float*)d_in[17];
    const float* h2w = (const float*)d_in[18];
    const float* h2b = (const float*)d_in[19];
    bf16* ws = (bf16*)d_ws;

    pack_weights<<<dim3((2 * WTOT + 255) / 256 / 2), dim3(256), 0, stream>>>(
        w01, wd0, w02, w11, w12, w21, w22, ws);

    tcn_entmax_kernel<<<dim3(TPQ * BQ), dim3(TPB), 0, stream>>>(
        src, trg, ws, b01, bd0, b02, b11, b12, b21, b22,
        h1w, h1b, h2w, h2b, (float*)d_out);
}

// Round 3
// 642.822 us; speedup vs baseline: 13.5917x; 1.1782x over previous
//
#include <hip/hip_runtime.h>
#include <math.h>

typedef _Float16 f16;
typedef __attribute__((ext_vector_type(8))) _Float16 half8;
typedef __attribute__((ext_vector_type(4))) float f32x4;
typedef __attribute__((ext_vector_type(4))) float f4;

#define TPB 512
#define TPQ 24
#define BQ 128
#define LSQ 168
#define DIN 64
#define CH 128

// ws element offsets (fp16 elements), fragment-packed weights
#define E0 0        /* w01: 128x64x3  -> 24576 */
#define ED 24576    /* wd0: 128x64x1  -> 8192  */
#define E1 32768    /* w02 */
#define E2 81920    /* w11 */
#define E3 131072   /* w12 */
#define E4 180224   /* w21 */
#define E5 229376   /* w22 */
#define WTOT 278528

#define MFMA16(a, b, c) __builtin_amdgcn_mfma_f32_16x16x32_f16((a), (b), (c), 0, 0, 0)

// byte offset of element (row8, co) in a 128-wide swizzled Xt buffer (256B rows)
__device__ __forceinline__ int xb128(int r8, int co) {
    return r8 * 256 + ((((co >> 3) ^ (r8 & 7))) << 4) + ((co & 7) << 1);
}

// ---------------- weight fragment packing (runs once per launch) ----------------
extern "C" __global__ void pack_weights(
    const float* __restrict__ w01, const float* __restrict__ wd0,
    const float* __restrict__ w02, const float* __restrict__ w11,
    const float* __restrict__ w12, const float* __restrict__ w21,
    const float* __restrict__ w22, f16* __restrict__ ws)
{
    int e = blockIdx.x * 256 + threadIdx.x;
    if (e >= WTOT) return;
    const float* W; int CIN, KK, el;
    if (e < ED) { W = w01; CIN = 64; KK = 3; el = e; }
    else if (e < E1) { W = wd0; CIN = 64; KK = 1; el = e - ED; }
    else {
        int c = (e - E1) / 49152; el = (e - E1) % 49152; CIN = 128; KK = 3;
        W = (c == 0) ? w02 : (c == 1) ? w11 : (c == 2) ? w12 : (c == 3) ? w21 : w22;
    }
    const int KB = CIN / 32;
    const int frag = el >> 9, wi = el & 511, lane = wi >> 3, i = wi & 7;
    const int coT = frag / (KK * KB), rem = frag % (KK * KB);
    const int kk = rem / KB, kb = rem % KB;
    const int co = coT * 16 + (lane & 15);
    const int ci = kb * 32 + (lane >> 4) * 8 + i;
    ws[e] = (f16)W[(co * CIN + ci) * KK + kk];
}

// ---------------- MFMA conv phase ----------------
// out[w][co] = act( bias + sum_{kk,ci} W[co][ci][kk] * in[ci][w - (KK-1-kk)*DIL] )
// RES==1: residual read from outB (in-place, element owned by writer thread).
template<int CIN, int KK, int DIL, int RES, int RELU>
__device__ __forceinline__ void mfma_conv(
    const char* __restrict__ inB, char* __restrict__ outB,
    const f16* __restrict__ wsAll, int eoff,
    const float* __restrict__ bias, int tid)
{
    constexpr int KB = CIN / 32;
    constexpr int RGB = CIN * 2;       // row bytes of input buffer
    const int lane = tid & 63;
    const int wid = tid >> 6;
    const int cg = wid & 1;            // co-half: co in [cg*64, cg*64+64)
    const int wg = wid >> 1;           // w-tile group
    const int t0 = wg * 3;
    const int t1 = (wg == 3) ? 11 : (t0 + 3);
    const int colr = lane & 15;
    const int quad = lane >> 4;

    const half8* __restrict__ wp = (const half8*)(wsAll + eoff);
    half8 wf[4][KK][KB];
#pragma unroll
    for (int ct = 0; ct < 4; ++ct)
#pragma unroll
        for (int kk = 0; kk < KK; ++kk)
#pragma unroll
            for (int kb = 0; kb < KB; ++kb)
                wf[ct][kk][kb] = wp[((((cg * 4 + ct) * KK) + kk) * KB + kb) * 64 + lane];

    float bv[4];
#pragma unroll
    for (int ct = 0; ct < 4; ++ct) bv[ct] = bias[cg * 64 + ct * 16 + colr];

    for (int t = t0; t < t1; ++t) {
        const int w0 = t * 16;
        f32x4 acc0 = {0.f, 0.f, 0.f, 0.f}, acc1 = {0.f, 0.f, 0.f, 0.f};
        f32x4 acc2 = {0.f, 0.f, 0.f, 0.f}, acc3 = {0.f, 0.f, 0.f, 0.f};
        const int wr = w0 + colr + 8;
#pragma unroll
        for (int kk = 0; kk < KK; ++kk) {
            int row8 = wr - (KK - 1 - kk) * DIL;
            row8 = (row8 > 176) ? 176 : row8;
            const int rbase = row8 * RGB;
            const int sx = row8 & 7;
#pragma unroll
            for (int kb = 0; kb < KB; ++kb) {
                const int g = kb * 4 + quad;
                const half8 a = *(const half8*)(inB + rbase + ((g ^ sx) << 4));
                acc0 = MFMA16(a, wf[0][kk][kb], acc0);
                acc1 = MFMA16(a, wf[1][kk][kb], acc1);
                acc2 = MFMA16(a, wf[2][kk][kb], acc2);
                acc3 = MFMA16(a, wf[3][kk][kb], acc3);
            }
        }
#pragma unroll
        for (int ct = 0; ct < 4; ++ct) {
            const float av0 = (ct == 0) ? acc0[0] : (ct == 1) ? acc1[0] : (ct == 2) ? acc2[0] : acc3[0];
            const float av1 = (ct == 0) ? acc0[1] : (ct == 1) ? acc1[1] : (ct == 2) ? acc2[1] : acc3[1];
            const float av2 = (ct == 0) ? acc0[2] : (ct == 1) ? acc1[2] : (ct == 2) ? acc2[2] : acc3[2];
            const float av3 = (ct == 0) ? acc0[3] : (ct == 1) ? acc1[3] : (ct == 2) ? acc2[3] : acc3[3];
            const int co = cg * 64 + ct * 16 + colr;
            const float avs[4] = {av0, av1, av2, av3};
#pragma unroll
            for (int j = 0; j < 4; ++j) {
                const int w = w0 + quad * 4 + j;
                if (w < 169) {
                    const int r8 = w + 8;
                    float v = avs[j] + bv[ct];
                    if (RELU) v = fmaxf(v, 0.f);
                    if (RES)  v = fmaxf(v + (float)(*(const f16*)(outB + xb128(r8, co))), 0.f);
                    *(f16*)(outB + xb128(r8, co)) = (f16)v;
                }
            }
        }
    }
}

// ---------------- main fused kernel ----------------
extern "C" __global__ void __launch_bounds__(TPB, 2)
tcn_entmax_kernel(
    const float* __restrict__ src, const float* __restrict__ trg,
    const f16* __restrict__ ws,
    const float* __restrict__ b01, const float* __restrict__ bd0,
    const float* __restrict__ b02, const float* __restrict__ b11,
    const float* __restrict__ b12, const float* __restrict__ b21,
    const float* __restrict__ b22,
    const float* __restrict__ h1w, const float* __restrict__ h1b,
    const float* __restrict__ h2w, const float* __restrict__ h2b,
    float* __restrict__ out)
{
    // Xt layout: [row8 = w+8][ci], fp16, 16B-granule XOR swizzle: granule ^= (row8 & 7)
    __shared__ __align__(16) char sX0[177 * 128];   // 64-ch input window; reused as f32 scratch later
    __shared__ __align__(16) char sA[177 * 256];
    __shared__ __align__(16) char sB[177 * 256];

    const int tid = threadIdx.x;
    const int n = blockIdx.x;
    const int tp = n >> 7;
    const int b = n & 127;

    // ---- stage window (transposed + swizzled), zero left-pad rows ----
    const float* srcb = src + (size_t)b * LSQ * DIN;
    const float* trgb = trg + (size_t)b * TPQ * DIN;
    for (int e = tid; e < 169 * 8; e += TPB) {
        const int w = e >> 3, g = e & 7;
        const int t = tp + w;
        const float* p = (t < LSQ) ? (srcb + t * DIN + g * 8) : (trgb + (t - LSQ) * DIN + g * 8);
        const f4 f0 = *(const f4*)p;
        const f4 f1 = *(const f4*)(p + 4);
        half8 v;
        v[0] = (f16)f0[0]; v[1] = (f16)f0[1]; v[2] = (f16)f0[2]; v[3] = (f16)f0[3];
        v[4] = (f16)f1[0]; v[5] = (f16)f1[1]; v[6] = (f16)f1[2]; v[7] = (f16)f1[3];
        const int r8 = w + 8;
        *(half8*)(sX0 + r8 * 128 + ((g ^ (r8 & 7)) << 4)) = v;
    }
    if (tid < 320) {
        const half8 z = {};
        if (tid < 64)       *(half8*)(sX0 + tid * 16) = z;
        else if (tid < 192) *(half8*)(sA + (tid - 64) * 16) = z;
        else                *(half8*)(sB + (tid - 192) * 16) = z;
    }
    __syncthreads();

    // ---- TCN block 0 (dil 1, downsample residual) ----
    mfma_conv<64, 3, 1, 0, 1>(sX0, sA, ws, E0, b01, tid);   // h1 -> sA
    mfma_conv<64, 1, 1, 0, 0>(sX0, sB, ws, ED, bd0, tid);   // ds residual -> sB (no relu)
    __syncthreads();
    mfma_conv<128, 3, 1, 1, 1>(sA, sB, ws, E1, b02, tid);   // block0 out -> sB (in-place res)
    __syncthreads();
    // ---- TCN block 1 (dil 2, identity residual) ----
    mfma_conv<128, 3, 2, 0, 1>(sB, sA, ws, E2, b11, tid);
    __syncthreads();
    mfma_conv<128, 3, 2, 1, 1>(sA, sB, ws, E3, b12, tid);   // block1 out -> sB
    __syncthreads();
    // ---- TCN block 2 (dil 4, identity residual) ----
    mfma_conv<128, 3, 4, 0, 1>(sB, sA, ws, E4, b21, tid);
    __syncthreads();
    mfma_conv<128, 3, 4, 1, 1>(sA, sB, ws, E5, b22, tid);   // final out -> sB
    __syncthreads();

    // ---- attention + entmax15 + heads; tcn out in sB (transposed, swizzled) ----
    float* fscr = reinterpret_cast<float*>(sX0);
    float* xe   = fscr;          // 168 raw scores
    float* xs   = fscr + 168;    // 168 sorted desc (raw)
    float* ssc  = fscr + 336;    // 168 entmax probs
    float* qv   = fscr + 504;    // 128
    float* cv   = fscr + 632;    // 128
    float* red1 = fscr + 768;    // 256
    float* red2 = fscr + 1024;   // 256

    if (tid < CH) qv[tid] = (float)(*(const f16*)(sB + xb128(176, tid)));
    __syncthreads();

    if (tid < LSQ) {
        const int r8 = tid + 8, sx = r8 & 7;
        float s = 0.f;
#pragma unroll
        for (int S = 0; S < 16; ++S) {
            const half8 kvv = *(const half8*)(sB + r8 * 256 + (S << 4));
            const float* qp = qv + (S ^ sx) * 8;
#pragma unroll
            for (int j = 0; j < 8; ++j) s = fmaf((float)kvv[j], qp[j], s);
        }
        xe[tid] = s;
    }
    __syncthreads();

    // rank-sort raw scores (rank invariant under the (x-max)/2 transform)
    if (tid < LSQ) {
        const float v = xe[tid];
        int r = 0;
        for (int m2 = 0; m2 < LSQ; ++m2) {
            const float u = xe[m2];
            r += (u > v) || ((u == v) && (m2 < tid));
        }
        xs[r] = v;
    }
    __syncthreads();

    // single-wave entmax threshold: cumsum scan + tau + support, no internal barriers
    if (tid < 64) {
        const int lane = tid;
        const float mx = xs[0];
        const int i0 = lane * 3;
        const float a0 = (i0     < LSQ) ? (xs[i0]     - mx) * 0.5f : 0.f;
        const float a1 = (i0 + 1 < LSQ) ? (xs[i0 + 1] - mx) * 0.5f : 0.f;
        const float a2 = (i0 + 2 < LSQ) ? (xs[i0 + 2] - mx) * 0.5f : 0.f;
        const float s1 = a0, s2 = a0 + a1, s3 = a0 + a1 + a2;
        const float q1 = a0 * a0, q2 = q1 + a1 * a1, q3 = q2 + a2 * a2;
        float ts = s3, tq = q3;
#pragma unroll
        for (int o = 1; o < 64; o <<= 1) {
            const float us = __shfl_up(ts, o);
            const float uq = __shfl_up(tq, o);
            if (lane >= o) { ts += us; tq += uq; }
        }
        const float eS = ts - s3, eQ = tq - q3;
        float tau0v, tau1v, tau2v; int ind = 0;
#define TAUC(CIDX, CS, CQ, AV, TVAR) { \
        const float rho = (float)(i0 + CIDX + 1); \
        const float mean = (CS) / rho; \
        const float msq = (CQ) / rho; \
        const float ssv = rho * (msq - mean * mean); \
        float delta = (1.f - ssv) / rho; \
        delta = delta > 0.f ? delta : 0.f; \
        TVAR = mean - sqrtf(delta); \
        if (i0 + CIDX < LSQ && TVAR <= (AV)) ++ind; }
        TAUC(0, eS + s1, eQ + q1, a0, tau0v)
        TAUC(1, eS + s2, eQ + q2, a1, tau1v)
        TAUC(2, eS + s3, eQ + q3, a2, tau2v)
#undef TAUC
#pragma unroll
        for (int o = 32; o; o >>= 1) ind += __shfl_xor(ind, o);
        const int sm1 = ind - 1;
        if (lane == sm1 / 3) {
            const int c = sm1 - (sm1 / 3) * 3;
            red1[0] = (c == 0) ? tau0v : (c == 1) ? tau1v : tau2v;
        }
        if (lane == 0) red1[1] = mx;
    }
    __syncthreads();

    const float tau_star = red1[0];
    const float mxv = red1[1];
    if (tid < LSQ) {
        float v = (xe[tid] - mxv) * 0.5f - tau_star;
        v = fmaxf(v, 0.f);
        ssc[tid] = v * v;
    }
    __syncthreads();

    // context vector c = sum_l score_l * kv[l][:]
    if (tid < CH) {
        float a = 0.f;
        const int gco = tid >> 3, bo = (tid & 7) << 1;
        for (int l = 0; l < LSQ; ++l) {
            const int r8 = l + 8;
            a = fmaf(ssc[l], (float)(*(const f16*)(sB + r8 * 256 + (((gco ^ (r8 & 7))) << 4) + bo)), a);
        }
        cv[tid] = a;
    }
    __syncthreads();

    // heads: cc = [c, q]; y1 = h1w.cc + h1b ; y2 = softplus(h2w.cc + h2b)
    if (tid < 2 * CH) {
        const float x = (tid < CH) ? cv[tid] : qv[tid - CH];
        red1[tid] = h1w[tid] * x;
        red2[tid] = h2w[tid] * x;
    }
    __syncthreads();
    if (tid < 64) {
        float s1 = red1[tid] + red1[tid + 64] + red1[tid + 128] + red1[tid + 192];
        float s2 = red2[tid] + red2[tid + 64] + red2[tid + 128] + red2[tid + 192];
#pragma unroll
        for (int o = 32; o; o >>= 1) {
            s1 += __shfl_xor(s1, o);
            s2 += __shfl_xor(s2, o);
        }
        if (tid == 0) {
            const float y1 = s1 + h1b[0];
            const float z  = s2 + h2b[0];
            const float sp = (z > 0.f) ? (z + log1pf(expf(-z))) : log1pf(expf(z));
            out[b * TPQ + tp] = y1;
            out[BQ * TPQ + b * TPQ + tp] = sp;
        }
    }
}

extern "C" void kernel_launch(void* const* d_in, const int* in_sizes, int n_in,
                              void* d_out, int out_size, void* d_ws, size_t ws_size,
                              hipStream_t stream) {
    const float* src = (const float*)d_in[0];
    const float* trg = (const float*)d_in[1];
    const float* w01 = (const float*)d_in[2];
    const float* b01 = (const float*)d_in[3];
    const float* w02 = (const float*)d_in[4];
    const float* b02 = (const float*)d_in[5];
    const float* wd0 = (const float*)d_in[6];
    const float* bd0 = (const float*)d_in[7];
    const float* w11 = (const float*)d_in[8];
    const float* b11 = (const float*)d_in[9];
    const float* w12 = (const float*)d_in[10];
    const float* b12 = (const float*)d_in[11];
    const float* w21 = (const float*)d_in[12];
    const float* b21 = (const float*)d_in[13];
    const float* w22 = (const float*)d_in[14];
    const float* b22 = (const float*)d_in[15];
    const float* h1w = (const float*)d_in[16];
    const float* h1b = (const float*)d_in[17];
    const float* h2w = (const float*)d_in[18];
    const float* h2b = (const float*)d_in[19];
    f16* ws = (f16*)d_ws;

    pack_weights<<<dim3((WTOT + 255) / 256), dim3(256), 0, stream>>>(
        w01, wd0, w02, w11, w12, w21, w22, ws);

    tcn_entmax_kernel<<<dim3(TPQ * BQ), dim3(TPB), 0, stream>>>(
        src, trg, ws, b01, bd0, b02, b11, b12, b21, b22,
        h1w, h1b, h2w, h2b, (float*)d_out);
}

// Round 4
// 168.036 us; speedup vs baseline: 51.9949x; 3.8255x over previous
//
#include <hip/hip_runtime.h>
#include <math.h>

typedef _Float16 f16;
typedef __attribute__((ext_vector_type(8))) _Float16 half8;
typedef __attribute__((ext_vector_type(4))) float f32x4;
typedef __attribute__((ext_vector_type(4))) float f4;

#define TPQ 24
#define BQ 128
#define LSQ 168

// ws element offsets (fp16 elements)
#define E0 0        /* w01 frags */
#define ED 24576    /* wd0 */
#define E1 32768    /* w02 */
#define E2 81920    /* w11 */
#define E3 131072   /* w12 */
#define E4 180224   /* w21 */
#define E5 229376   /* w22 */
#define WTOT 278528
#define OG2 278528                       /* block2 out: [128][192][128] */
#define OG1 3424256                      /* block1 out: [128][52][128]  */
#define OG0 4276224                      /* block0 out: [128][36][128]  */
/* end: 4866048 el = 9.73 MB */

#define MFMA16(a, b, c) __builtin_amdgcn_mfma_f32_16x16x32_f16((a), (b), (c), 0, 0, 0)

// ---------------- weight fragment packing ----------------
extern "C" __global__ void pack_weights(
    const float* __restrict__ w01, const float* __restrict__ wd0,
    const float* __restrict__ w02, const float* __restrict__ w11,
    const float* __restrict__ w12, const float* __restrict__ w21,
    const float* __restrict__ w22, f16* __restrict__ ws)
{
    int e = blockIdx.x * 256 + threadIdx.x;
    if (e >= WTOT) return;
    const float* W; int CIN, KK, el;
    if (e < ED) { W = w01; CIN = 64; KK = 3; el = e; }
    else if (e < E1) { W = wd0; CIN = 64; KK = 1; el = e - ED; }
    else {
        int c = (e - E1) / 49152; el = (e - E1) % 49152; CIN = 128; KK = 3;
        W = (c == 0) ? w02 : (c == 1) ? w11 : (c == 2) ? w12 : (c == 3) ? w21 : w22;
    }
    const int KB = CIN / 32;
    const int frag = el >> 9, wi = el & 511, lane = wi >> 3, i = wi & 7;
    const int coT = frag / (KK * KB), rem = frag % (KK * KB);
    const int kk = rem / KB, kb = rem % KB;
    const int co = coT * 16 + (lane & 15);
    const int ci = kb * 32 + (lane >> 4) * 8 + i;
    ws[e] = (f16)W[(co * CIN + ci) * KK + kk];
}

// ---------------- kernel A: global TCN over full srctrg ----------------
// LDS buffers: rows r8 = local_w + 8 (8 zero pad rows), swizzled 16B granules: slot = g ^ (r8&7)
template<int CIN, int KK, int DIL, int RES, int RELU>
__device__ __forceinline__ void phaseA(
    const char* __restrict__ inb, char* __restrict__ outb,
    const f16* __restrict__ ws, int eoff, const float* __restrict__ bias, int tid)
{
    constexpr int KB = CIN / 32;
    constexpr int RB = CIN * 2;
    const int lane = tid & 63, wid = tid >> 6;
    const int cg = wid & 3, wg = wid >> 2;
    const int colr = lane & 15, quad = lane >> 4;
    const half8* __restrict__ wp = (const half8*)(ws + eoff);
    half8 wf[2][KK][KB];
#pragma unroll
    for (int ct = 0; ct < 2; ++ct)
#pragma unroll
        for (int kk = 0; kk < KK; ++kk)
#pragma unroll
            for (int kb = 0; kb < KB; ++kb)
                wf[ct][kk][kb] = wp[((((cg * 2 + ct) * KK) + kk) * KB + kb) * 64 + lane];
    const float bv0 = bias[cg * 32 + colr], bv1 = bias[cg * 32 + 16 + colr];
    const int t0 = wg ? 3 : 0, t1 = wg ? 5 : 3;
    for (int t = t0; t < t1; ++t) {
        const int w = t * 16 + colr;
        f32x4 a0 = {0.f, 0.f, 0.f, 0.f}, a1 = {0.f, 0.f, 0.f, 0.f};
#pragma unroll
        for (int kk = 0; kk < KK; ++kk) {
            const int r8 = w + 8 - (KK - 1 - kk) * DIL;   // >= 0 always
            const int rb = r8 * RB, sx = r8 & 7;
#pragma unroll
            for (int kb = 0; kb < KB; ++kb) {
                const half8 a = *(const half8*)(inb + rb + ((((kb * 4 + quad) ^ sx)) << 4));
                a0 = MFMA16(a, wf[0][kk][kb], a0);
                a1 = MFMA16(a, wf[1][kk][kb], a1);
            }
        }
#pragma unroll
        for (int ct = 0; ct < 2; ++ct) {
            const float bv = ct ? bv1 : bv0;
            const int co = cg * 32 + ct * 16 + colr;
#pragma unroll
            for (int j = 0; j < 4; ++j) {
                const int r8o = t * 16 + quad * 4 + j + 8;
                char* p = outb + r8o * 256 + ((((co >> 3) ^ (r8o & 7))) << 4) + ((co & 7) << 1);
                float v = (ct ? a1[j] : a0[j]) + bv;
                if (RELU) v = fmaxf(v, 0.f);
                if (RES)  v = fmaxf(v + (float)*(const f16*)p, 0.f);
                *(f16*)p = (f16)v;
            }
        }
    }
}

extern "C" __global__ void __launch_bounds__(512, 4)
tcn_global(const float* __restrict__ src, const float* __restrict__ trg,
           f16* __restrict__ ws,
           const float* __restrict__ b01, const float* __restrict__ bd0,
           const float* __restrict__ b02, const float* __restrict__ b11,
           const float* __restrict__ b12, const float* __restrict__ b21,
           const float* __restrict__ b22)
{
    __shared__ __align__(16) char sX[88 * 128];
    __shared__ __align__(16) char sH1[88 * 256];
    __shared__ __align__(16) char sH2[88 * 256];
    const int tid = threadIdx.x;
    const int b = blockIdx.x >> 2, chunk = blockIdx.x & 3;
    const int u0 = chunk * 48;
    const float* srcb = src + (size_t)b * LSQ * 64;
    const float* trgb = trg + (size_t)b * TPQ * 64;

    for (int e = tid; e < 80 * 8; e += 512) {
        const int w = e >> 3, gg = e & 7;
        const int p = u0 - 28 + w;
        half8 v = {};
        if (p >= 0 && p < 192) {
            const float* ptr = (p < 168) ? (srcb + p * 64 + gg * 8) : (trgb + (p - 168) * 64 + gg * 8);
            const f4 f0 = *(const f4*)ptr; const f4 f1 = *(const f4*)(ptr + 4);
            v[0] = (f16)f0[0]; v[1] = (f16)f0[1]; v[2] = (f16)f0[2]; v[3] = (f16)f0[3];
            v[4] = (f16)f1[0]; v[5] = (f16)f1[1]; v[6] = (f16)f1[2]; v[7] = (f16)f1[3];
        }
        const int r8 = w + 8;
        *(half8*)(sX + r8 * 128 + ((gg ^ (r8 & 7)) << 4)) = v;
    }
    if (tid < 320) {
        const half8 z = {};
        if (tid < 64)       *(half8*)(sX + tid * 16) = z;
        else if (tid < 192) *(half8*)(sH1 + (tid - 64) * 16) = z;
        else                *(half8*)(sH2 + (tid - 192) * 16) = z;
    }
    __syncthreads();

    phaseA<64, 3, 1, 0, 1>(sX, sH1, ws, E0, b01, tid);
    phaseA<64, 1, 1, 0, 0>(sX, sH2, ws, ED, bd0, tid);
    __syncthreads();
    phaseA<128, 3, 1, 1, 1>(sH1, sH2, ws, E1, b02, tid);   // block0 out -> sH2
    __syncthreads();
    phaseA<128, 3, 2, 0, 1>(sH2, sH1, ws, E2, b11, tid);
    if (chunk == 0) {   // block0 out rows abs [0,36) -> G0 (reads sH2 only; safe alongside P4)
        for (int e = tid; e < 36 * 16; e += 512) {
            const int p = e >> 4, gc = e & 15, r8 = p + 36;
            const half8 v = *(const half8*)(sH2 + r8 * 256 + ((gc ^ (r8 & 7)) << 4));
            *(half8*)(ws + OG0 + (size_t)(b * 36 + p) * 128 + gc * 8) = v;
        }
    }
    __syncthreads();
    phaseA<128, 3, 2, 1, 1>(sH1, sH2, ws, E3, b12, tid);   // block1 out -> sH2
    __syncthreads();
    phaseA<128, 3, 4, 0, 1>(sH2, sH1, ws, E4, b21, tid);
    if (chunk == 0) {   // block1 out rows abs [0,52) -> G1
        for (int e = tid; e < 52 * 16; e += 512) {
            const int p = e >> 4, gc = e & 15, r8 = p + 36;
            const half8 v = *(const half8*)(sH2 + r8 * 256 + ((gc ^ (r8 & 7)) << 4));
            *(half8*)(ws + OG1 + (size_t)(b * 52 + p) * 128 + gc * 8) = v;
        }
    }
    __syncthreads();
    phaseA<128, 3, 4, 1, 1>(sH1, sH2, ws, E5, b22, tid);   // block2 out -> sH2
    __syncthreads();
    for (int e = tid; e < 48 * 16; e += 512) {              // block2 out abs [u0,u0+48) -> G2
        const int pl = e >> 4, gc = e & 15, r8 = pl + 36;
        const int p = u0 + pl;
        const half8 v = *(const half8*)(sH2 + r8 * 256 + ((gc ^ (r8 & 7)) << 4));
        *(half8*)(ws + OG2 + (size_t)(b * 192 + p) * 128 + gc * 8) = v;
    }
}

// ---------------- kernel BC: per-window boundary cone + attention ----------------
// 4 windows per block. Packed M-tiles: m -> (g = m/WPG, w = m%WPG). Buffers: 256B rows,
// row index = g*SROW + w, granule slot = gc ^ (row&7). Negative taps -> zero row.
template<int CIN, int KK, int DIL, int WPG, int SIN, int SOUT, int RES, int RELU>
__device__ __forceinline__ void bc_conv(
    const char* __restrict__ inb, char* __restrict__ outb, const char* __restrict__ zrp,
    const f16* __restrict__ ws, int eoff, const float* __restrict__ bias, int tid)
{
    constexpr int KB = CIN / 32;
    constexpr int RB = CIN * 2;
    constexpr int NT = (4 * WPG) / 16;
    const int lane = tid & 63, wid = tid >> 6;
    const int colr = lane & 15, quad = lane >> 4;
    const half8* __restrict__ wp = (const half8*)(ws + eoff);
    half8 wf[2][KK][KB];
#pragma unroll
    for (int ct = 0; ct < 2; ++ct)
#pragma unroll
        for (int kk = 0; kk < KK; ++kk)
#pragma unroll
            for (int kb = 0; kb < KB; ++kb)
                wf[ct][kk][kb] = wp[((((wid * 2 + ct) * KK) + kk) * KB + kb) * 64 + lane];
    const float bv0 = bias[wid * 32 + colr], bv1 = bias[wid * 32 + 16 + colr];
    for (int t = 0; t < NT; ++t) {
        const int m = t * 16 + colr;
        const int g = m / WPG, w = m - g * WPG;
        f32x4 a0 = {0.f, 0.f, 0.f, 0.f}, a1 = {0.f, 0.f, 0.f, 0.f};
#pragma unroll
        for (int kk = 0; kk < KK; ++kk) {
            const int wq = w - (KK - 1 - kk) * DIL;
            const int row = g * SIN + wq;
            const char* rb = (wq < 0) ? zrp : (inb + row * RB);
            const int sx = (wq < 0) ? 0 : (row & 7);
#pragma unroll
            for (int kb = 0; kb < KB; ++kb) {
                const half8 a = *(const half8*)(rb + ((((kb * 4 + quad) ^ sx)) << 4));
                a0 = MFMA16(a, wf[0][kk][kb], a0);
                a1 = MFMA16(a, wf[1][kk][kb], a1);
            }
        }
#pragma unroll
        for (int ct = 0; ct < 2; ++ct) {
            const float bv = ct ? bv1 : bv0;
            const int co = wid * 32 + ct * 16 + colr;
#pragma unroll
            for (int j = 0; j < 4; ++j) {
                const int mo = t * 16 + quad * 4 + j;
                const int go = mo / WPG, wo = mo - go * WPG;
                const int row = go * SOUT + wo;
                char* p = outb + row * 256 + ((((co >> 3) ^ (row & 7))) << 4) + ((co & 7) << 1);
                float v = (ct ? a1[j] : a0[j]) + bv;
                if (RELU) v = fmaxf(v, 0.f);
                if (RES)  v = fmaxf(v + (float)*(const f16*)p, 0.f);
                *(f16*)p = (f16)v;
            }
        }
    }
}

// P2: block0out = relu( relu(conv2b0(cb1)+b02) + convd(x)+bd0 ) -> BufB rows g*28+w
__device__ __forceinline__ void bc_p2(
    const char* __restrict__ bx, const char* __restrict__ cb1, char* __restrict__ outB,
    const char* __restrict__ zrp, const f16* __restrict__ ws,
    const float* __restrict__ b02, const float* __restrict__ bd0, int tid)
{
    const int lane = tid & 63, wid = tid >> 6;
    const int colr = lane & 15, quad = lane >> 4;
    const half8* __restrict__ wpA = (const half8*)(ws + E1);
    const half8* __restrict__ wpD = (const half8*)(ws + ED);
    half8 wfa[2][3][4], wfd[2][2];
#pragma unroll
    for (int ct = 0; ct < 2; ++ct) {
#pragma unroll
        for (int kk = 0; kk < 3; ++kk)
#pragma unroll
            for (int kb = 0; kb < 4; ++kb)
                wfa[ct][kk][kb] = wpA[((((wid * 2 + ct) * 3) + kk) * 4 + kb) * 64 + lane];
#pragma unroll
        for (int kb = 0; kb < 2; ++kb)
            wfd[ct][kb] = wpD[((wid * 2 + ct) * 2 + kb) * 64 + lane];
    }
    const float ba0 = b02[wid * 32 + colr], ba1 = b02[wid * 32 + 16 + colr];
    const float bd0v = bd0[wid * 32 + colr], bd1v = bd0[wid * 32 + 16 + colr];
    const int m = colr;
    const int g = m >> 2, w = m & 3;
    f32x4 a0 = {0.f,0.f,0.f,0.f}, a1 = {0.f,0.f,0.f,0.f};
    f32x4 d0 = {0.f,0.f,0.f,0.f}, d1 = {0.f,0.f,0.f,0.f};
#pragma unroll
    for (int kk = 0; kk < 3; ++kk) {
        const int wq = w - (2 - kk);
        const int row = g * 4 + wq;
        const char* rb = (wq < 0) ? zrp : (cb1 + row * 256);
        const int sx = (wq < 0) ? 0 : (row & 7);
#pragma unroll
        for (int kb = 0; kb < 4; ++kb) {
            const half8 a = *(const half8*)(rb + ((((kb * 4 + quad) ^ sx)) << 4));
            a0 = MFMA16(a, wfa[0][kk][kb], a0);
            a1 = MFMA16(a, wfa[1][kk][kb], a1);
        }
    }
    {
        const int row = g * 4 + w;
        const char* rb = bx + row * 128;
        const int sx = row & 7;
#pragma unroll
        for (int kb = 0; kb < 2; ++kb) {
            const half8 x = *(const half8*)(rb + ((((kb * 4 + quad) ^ sx)) << 4));
            d0 = MFMA16(x, wfd[0][kb], d0);
            d1 = MFMA16(x, wfd[1][kb], d1);
        }
    }
#pragma unroll
    for (int ct = 0; ct < 2; ++ct) {
        const int co = wid * 32 + ct * 16 + colr;
#pragma unroll
        for (int j = 0; j < 4; ++j) {
            const int mo = quad * 4 + j;
            const int go = mo >> 2, wo = mo & 3;
            const int row = go * 28 + wo;
            char* p = outB + row * 256 + ((((co >> 3) ^ (row & 7))) << 4) + ((co & 7) << 1);
            const float ca = (ct ? a1[j] : a0[j]) + (ct ? ba1 : ba0);
            const float cd = (ct ? d1[j] : d0[j]) + (ct ? bd1v : bd0v);
            *(f16*)p = (f16)fmaxf(fmaxf(ca, 0.f) + cd, 0.f);
        }
    }
}

extern "C" __global__ void __launch_bounds__(256, 2)
tcn_bdattn(const float* __restrict__ src, const f16* __restrict__ ws,
           const float* __restrict__ b01, const float* __restrict__ bd0,
           const float* __restrict__ b02, const float* __restrict__ b11,
           const float* __restrict__ b12, const float* __restrict__ b21,
           const float* __restrict__ b22,
           const float* __restrict__ h1w, const float* __restrict__ h1b,
           const float* __restrict__ h2w, const float* __restrict__ h2b,
           float* __restrict__ out)
{
    __shared__ __align__(16) char BufB[112 * 256];
    __shared__ __align__(16) char BufC[112 * 256];
    __shared__ __align__(16) char sbx[16 * 128];
    __shared__ __align__(16) char scb1[16 * 256];
    __shared__ __align__(16) char zr[256];
    __shared__ float qf[512];
    __shared__ float sc[672];
    __shared__ float xs[672];
    __shared__ float taus[4];

    const int tid = threadIdx.x, lane = tid & 63, wid = tid >> 6;
    const int n0 = blockIdx.x << 2;
    const int tp = n0 >> 7, b0 = n0 & 127;

    if (tid < 16) *(half8*)(zr + tid * 16) = half8{};
    if (tid < 128) {   // stage x rows [0,4) per window
        const int g = tid >> 5, w = (tid >> 3) & 3, gg = tid & 7;
        const float* ptr = src + ((size_t)(b0 + g) * LSQ + (tp + w)) * 64 + gg * 8;
        const f4 f0 = *(const f4*)ptr; const f4 f1 = *(const f4*)(ptr + 4);
        half8 v;
        v[0] = (f16)f0[0]; v[1] = (f16)f0[1]; v[2] = (f16)f0[2]; v[3] = (f16)f0[3];
        v[4] = (f16)f1[0]; v[5] = (f16)f1[1]; v[6] = (f16)f1[2]; v[7] = (f16)f1[3];
        const int row = g * 4 + w;
        *(half8*)(sbx + row * 128 + ((gg ^ (row & 7)) << 4)) = v;
    }
    for (int e = tid; e < 512; e += 256) {   // G0 -> BufB rows g*28+[4,12)
        const int g = e >> 7, pw = 4 + ((e >> 4) & 7), gc = e & 15;
        const half8 v = *(const half8*)(ws + OG0 + (size_t)((b0 + g) * 36 + (tp + pw)) * 128 + gc * 8);
        const int row = g * 28 + pw;
        *(half8*)(BufB + row * 256 + ((gc ^ (row & 7)) << 4)) = v;
    }
    for (int e = tid; e < 1024; e += 256) {  // G1 -> BufB rows g*28+[12,28)
        const int g = e >> 8, pw = 12 + ((e >> 4) & 15), gc = e & 15;
        const half8 v = *(const half8*)(ws + OG1 + (size_t)((b0 + g) * 52 + (tp + pw)) * 128 + gc * 8);
        const int row = g * 28 + pw;
        *(half8*)(BufB + row * 256 + ((gc ^ (row & 7)) << 4)) = v;
    }
    for (int e = tid; e < 512; e += 256) {   // q (abs tp+168) -> qf (f32)
        const int g = e >> 7, c = e & 127;
        qf[e] = (float)ws[OG2 + (size_t)((b0 + g) * 192 + tp + 168) * 128 + c];
    }
    __syncthreads();

    bc_conv<64, 3, 1, 4, 4, 4, 0, 1>(sbx, scb1, zr, ws, E0, b01, tid);      // conv1b0 -> cb1
    __syncthreads();
    bc_p2(sbx, scb1, BufB, zr, ws, b02, bd0, tid);                          // block0 -> BufB[0,4)
    __syncthreads();
    bc_conv<128, 3, 2, 12, 28, 28, 0, 1>(BufB, BufC, zr, ws, E2, b11, tid); // conv1b1 -> BufC
    __syncthreads();
    bc_conv<128, 3, 2, 12, 28, 28, 1, 1>(BufC, BufB, zr, ws, E3, b12, tid); // block1 -> BufB[0,12)
    __syncthreads();
    bc_conv<128, 3, 4, 28, 28, 28, 0, 1>(BufB, BufC, zr, ws, E4, b21, tid); // conv1b2 -> BufC
    __syncthreads();
    bc_conv<128, 3, 4, 28, 28, 28, 1, 1>(BufC, BufB, zr, ws, E5, b22, tid); // block2 -> BufB[0,28)
    __syncthreads();

    // ---- attention per wave (g = wid) ----
    const int g = wid;
    const int b = b0 + g;
    const f16* __restrict__ g2r = ws + OG2 + ((size_t)b * 192 + tp) * 128;

    for (int it = 0; it < 3; ++it) {
        const int w = it * 64 + lane;
        if (w < LSQ) {
            float s = 0.f;
            if (w < 28) {
                const int row = g * 28 + w, sx = row & 7;
                const char* rb = BufB + row * 256;
#pragma unroll
                for (int gc = 0; gc < 16; ++gc) {
                    const half8 kv = *(const half8*)(rb + ((gc ^ sx) << 4));
#pragma unroll
                    for (int j = 0; j < 8; ++j) s = fmaf((float)kv[j], qf[g * 128 + gc * 8 + j], s);
                }
            } else {
                const half8* rb = (const half8*)(g2r + (size_t)w * 128);
#pragma unroll
                for (int gc = 0; gc < 16; ++gc) {
                    const half8 kv = rb[gc];
#pragma unroll
                    for (int j = 0; j < 8; ++j) s = fmaf((float)kv[j], qf[g * 128 + gc * 8 + j], s);
                }
            }
            sc[g * 168 + w] = s;
        }
    }
    __syncthreads();

    // rank-sort (desc, stable)
    const int i0 = lane * 3;
    {
        const float v0 = (i0 < LSQ) ? sc[g * 168 + i0] : 0.f;
        const float v1 = (i0 + 1 < LSQ) ? sc[g * 168 + i0 + 1] : 0.f;
        const float v2 = (i0 + 2 < LSQ) ? sc[g * 168 + i0 + 2] : 0.f;
        int r0 = 0, r1 = 0, r2 = 0;
        for (int m2 = 0; m2 < LSQ; ++m2) {
            const float u = sc[g * 168 + m2];
            r0 += (u > v0) || ((u == v0) && (m2 < i0));
            r1 += (u > v1) || ((u == v1) && (m2 < i0 + 1));
            r2 += (u > v2) || ((u == v2) && (m2 < i0 + 2));
        }
        if (i0 < LSQ)     xs[g * 168 + r0] = v0;
        if (i0 + 1 < LSQ) xs[g * 168 + r1] = v1;
        if (i0 + 2 < LSQ) xs[g * 168 + r2] = v2;
    }
    __syncthreads();

    // per-wave entmax threshold: shfl scan over sorted values
    {
        const float mx = xs[g * 168];
        const float a0 = (i0 < LSQ) ? (xs[g * 168 + i0] - mx) * 0.5f : 0.f;
        const float a1 = (i0 + 1 < LSQ) ? (xs[g * 168 + i0 + 1] - mx) * 0.5f : 0.f;
        const float a2 = (i0 + 2 < LSQ) ? (xs[g * 168 + i0 + 2] - mx) * 0.5f : 0.f;
        const float s1 = a0, s2 = a0 + a1, s3 = a0 + a1 + a2;
        const float q1 = a0 * a0, q2 = q1 + a1 * a1, q3 = q2 + a2 * a2;
        float ts = s3, tq = q3;
#pragma unroll
        for (int o = 1; o < 64; o <<= 1) {
            const float us = __shfl_up(ts, o);
            const float uq = __shfl_up(tq, o);
            if (lane >= o) { ts += us; tq += uq; }
        }
        const float eS = ts - s3, eQ = tq - q3;
        float tau0v, tau1v, tau2v; int ind = 0;
#define TAUC(CIDX, CS, CQ, AV, TVAR) { \
        const float rho = (float)(i0 + CIDX + 1); \
        const float mean = (CS) / rho; \
        const float msq = (CQ) / rho; \
        const float ssv = rho * (msq - mean * mean); \
        float delta = (1.f - ssv) / rho; \
        delta = delta > 0.f ? delta : 0.f; \
        TVAR = mean - sqrtf(delta); \
        if (i0 + CIDX < LSQ && TVAR <= (AV)) ++ind; }
        TAUC(0, eS + s1, eQ + q1, a0, tau0v)
        TAUC(1, eS + s2, eQ + q2, a1, tau1v)
        TAUC(2, eS + s3, eQ + q3, a2, tau2v)
#undef TAUC
#pragma unroll
        for (int o = 32; o; o >>= 1) ind += __shfl_xor(ind, o);
        const int sm1 = ind - 1;
        if (lane == sm1 / 3) {
            const int c = sm1 - (sm1 / 3) * 3;
            taus[g] = (c == 0) ? tau0v : (c == 1) ? tau1v : tau2v;
        }
    }
    __syncthreads();

    // probs (overwrite sc)
    {
        const float mx = xs[g * 168];
        const float tau = taus[g];
        for (int it = 0; it < 3; ++it) {
            const int w = it * 64 + lane;
            if (w < LSQ) {
                float v = (sc[g * 168 + w] - mx) * 0.5f - tau;
                v = fmaxf(v, 0.f);
                sc[g * 168 + w] = v * v;
            }
        }
    }
    __syncthreads();

    // context + heads
    {
        const int c0 = lane * 2;
        float cv0 = 0.f, cv1 = 0.f;
        for (int w = 0; w < LSQ; ++w) {
            const float pw = sc[g * 168 + w];
            float k0, k1;
            if (w < 28) {
                const int row = g * 28 + w, sx = row & 7;
                const char* p = BufB + row * 256 + (((c0 >> 3) ^ sx) << 4) + ((c0 & 7) << 1);
                k0 = (float)*(const f16*)p;
                k1 = (float)*(const f16*)(p + 2);
            } else {
                const f16* p = g2r + (size_t)w * 128 + c0;
                k0 = (float)p[0];
                k1 = (float)p[1];
            }
            cv0 = fmaf(pw, k0, cv0);
            cv1 = fmaf(pw, k1, cv1);
        }
        const float q0 = qf[g * 128 + c0], q1 = qf[g * 128 + c0 + 1];
        float s1 = h1w[c0] * cv0 + h1w[c0 + 1] * cv1 + h1w[128 + c0] * q0 + h1w[128 + c0 + 1] * q1;
        float s2 = h2w[c0] * cv0 + h2w[c0 + 1] * cv1 + h2w[128 + c0] * q0 + h2w[128 + c0 + 1] * q1;
#pragma unroll
        for (int o = 32; o; o >>= 1) {
            s1 += __shfl_xor(s1, o);
            s2 += __shfl_xor(s2, o);
        }
        if (lane == 0) {
            const float y1 = s1 + h1b[0];
            const float z = s2 + h2b[0];
            const float sp = (z > 0.f) ? (z + log1pf(expf(-z))) : log1pf(expf(z));
            out[b * TPQ + tp] = y1;
            out[BQ * TPQ + b * TPQ + tp] = sp;
        }
    }
}

extern "C" void kernel_launch(void* const* d_in, const int* in_sizes, int n_in,
                              void* d_out, int out_size, void* d_ws, size_t ws_size,
                              hipStream_t stream) {
    const float* src = (const float*)d_in[0];
    const float* trg = (const float*)d_in[1];
    const float* w01 = (const float*)d_in[2];
    const float* b01 = (const float*)d_in[3];
    const float* w02 = (const float*)d_in[4];
    const float* b02 = (const float*)d_in[5];
    const float* wd0 = (const float*)d_in[6];
    const float* bd0 = (const float*)d_in[7];
    const float* w11 = (const float*)d_in[8];
    const float* b11 = (const float*)d_in[9];
    const float* w12 = (const float*)d_in[10];
    const float* b12 = (const float*)d_in[11];
    const float* w21 = (const float*)d_in[12];
    const float* b21 = (const float*)d_in[13];
    const float* w22 = (const float*)d_in[14];
    const float* b22 = (const float*)d_in[15];
    const float* h1w = (const float*)d_in[16];
    const float* h1b = (const float*)d_in[17];
    const float* h2w = (const float*)d_in[18];
    const float* h2b = (const float*)d_in[19];
    f16* ws = (f16*)d_ws;

    pack_weights<<<dim3((WTOT + 255) / 256), dim3(256), 0, stream>>>(
        w01, wd0, w02, w11, w12, w21, w22, ws);

    tcn_global<<<dim3(BQ * 4), dim3(512), 0, stream>>>(
        src, trg, ws, b01, bd0, b02, b11, b12, b21, b22);

    tcn_bdattn<<<dim3(TPQ * BQ / 4), dim3(256), 0, stream>>>(
        src, ws, b01, bd0, b02, b11, b12, b21, b22,
        h1w, h1b, h2w, h2b, (float*)d_out);
}